// Round 1
// baseline (196.097 us; speedup 1.0000x reference)
//
#include <hip/hip_runtime.h>

// SH message-passing inner product:
//   out[e][l] = sum_{j in irrep-block l} node_sh[row[e]][j] * node_sh[col[e]][j]
// SH_DIM = 64 (LMAX=7), block l spans features [l*l, (l+1)*(l+1)-1].
//
// Strategy: one wave (64 lanes) owns a chunk of 64 edges.
//  - coalesced index load: lane i holds row/col of edge e_base+i
//  - per edge k: broadcast ids (readlane), coalesced 256B row loads,
//    p = a*b, 6-step inclusive wave prefix sum, block sums via
//    P[end] - P[start-1], lanes 0..7 stage 8 results in LDS
//  - final coalesced global write: lane i stores edge (e_base+i)'s 8 floats.

#define WAVES_PER_BLOCK 4

__global__ __launch_bounds__(WAVES_PER_BLOCK * 64) void sh_msg_kernel(
    const int* __restrict__ row,
    const int* __restrict__ col,
    const float* __restrict__ sh,
    float* __restrict__ out,
    const int E)
{
    __shared__ float lds_out[WAVES_PER_BLOCK][64 * 8];

    const int lane = threadIdx.x & 63;
    const int wid  = threadIdx.x >> 6;
    const long wave_global = (long)blockIdx.x * WAVES_PER_BLOCK + wid;
    const long e_base = wave_global * 64;
    if (e_base >= E) return;

    // Coalesced edge-index load: lane i -> edge e_base + i.
    int r = 0, c = 0;
    if (e_base + lane < E) {
        r = row[e_base + lane];
        c = col[e_base + lane];
    }

    // Per-lane constants for the segmented-sum extraction (lanes 0..7 use them).
    const int ll = lane & 7;
    const int e1 = (ll + 1) * (ll + 1) - 1;   // inclusive end of block ll
    const int e0s = ll * ll - 1;              // inclusive end of previous block
    const int e0 = (e0s < 0) ? 0 : e0s;

    float* my = lds_out[wid];

    #pragma unroll 4
    for (int k = 0; k < 64; ++k) {
        const int rk = __shfl(r, k, 64);   // uniform lane -> readlane (SGPR)
        const int ck = __shfl(c, k, 64);
        const float a = sh[(long)rk * 64 + lane];  // coalesced 256B
        const float b = sh[(long)ck * 64 + lane];  // coalesced 256B
        float s = a * b;

        // Inclusive prefix sum across 64 lanes.
        #pragma unroll
        for (int d = 1; d < 64; d <<= 1) {
            const float t = __shfl_up(s, d, 64);
            if (lane >= d) s += t;
        }

        // Block sum for irrep ll: P[e1] - P[e0] (P[-1] := 0).
        const float hi = __shfl(s, e1, 64);
        const float lo = __shfl(s, e0, 64);
        if (lane < 8) {
            my[k * 8 + lane] = hi - ((ll == 0) ? 0.0f : lo);
        }
    }

    // Coalesced store: lane i writes the 8 outputs of edge e_base+i.
    if (e_base + lane < E) {
        const float4* src = (const float4*)(my + lane * 8);
        float4* dst = (float4*)(out + (e_base + lane) * 8);
        dst[0] = src[0];
        dst[1] = src[1];
    }
}

extern "C" void kernel_launch(void* const* d_in, const int* in_sizes, int n_in,
                              void* d_out, int out_size, void* d_ws, size_t ws_size,
                              hipStream_t stream) {
    const int* edge_index = (const int*)d_in[0];   // [2, E] int32
    const float* node_sh  = (const float*)d_in[1]; // [N, 64] f32
    float* out            = (float*)d_out;         // [E, 8] f32

    const int E = in_sizes[0] / 2;
    const int* row = edge_index;
    const int* col = edge_index + E;

    const int edges_per_block = WAVES_PER_BLOCK * 64;
    const int blocks = (E + edges_per_block - 1) / edges_per_block;

    sh_msg_kernel<<<blocks, WAVES_PER_BLOCK * 64, 0, stream>>>(row, col, node_sh, out, E);
}

// Round 2
// 108.740 us; speedup vs baseline: 1.8034x; 1.8034x over previous
//
#include <hip/hip_runtime.h>

// SH message-passing inner product:
//   out[e][l] = sum_{j in [l*l, (l+1)^2-1]} sh[row[e]][j] * sh[col[e]][j]
// SH_DIM = 64 (LMAX=7), 8 output irreps per edge.
//
// Structure (one wave owns 64 edges, processed in 4 rounds of 16):
//  phase A: per edge k, broadcast ids via readlane, wave loads the two
//           256B node rows coalesced (lane = feature), writes product to a
//           padded [16][65] LDS tile (bank-conflict-free).
//  phase B: transpose read — lane (sub,q) = (lane&15, lane>>4) reads the
//           16 features [16q,16q+16) of edge sub (conflict-free: 2 lanes/bank),
//           reduces the irrep segments in registers (shared subsums),
//           one ds_bpermute fixes the two blocks that cross feature 32/48
//           (l=5 spans 25..35, l=6 spans 36..48), stores straight to global.
// No barriers: producer/consumer are the same wave (in-order DS pipe).

#define WPB 4          // waves per block
#define TW  65         // LDS tile row stride in floats (64 + 1 pad)

__global__ __launch_bounds__(WPB * 64, 4) void sh_msg_kernel(
    const int*   __restrict__ row,
    const int*   __restrict__ col,
    const float* __restrict__ sh,
    float*       __restrict__ out,
    const int E)
{
    __shared__ float tile[WPB][16 * TW];

    const int lane = threadIdx.x & 63;
    const int wid  = threadIdx.x >> 6;
    const long e_base = ((long)blockIdx.x * WPB + wid) * 64;
    if (e_base >= E) return;

    // Coalesced edge-index load: lane i <-> edge e_base+i.
    int r = 0, c = 0;
    if (e_base + lane < (long)E) {
        r = row[e_base + lane];
        c = col[e_base + lane];
    }

    float* __restrict__ t = tile[wid];
    const int sub   = lane & 15;   // edge-within-round
    const int q     = lane >> 4;   // feature quarter
    const int rbase = sub * TW + q * 16;

    #pragma unroll
    for (int rd = 0; rd < 4; ++rd) {
        // ---- phase A: products for edges rd*16 .. rd*16+15 ----
        #pragma unroll
        for (int k = 0; k < 16; ++k) {
            const int rk = __shfl(r, rd * 16 + k, 64);   // constant lane -> v_readlane
            const int ck = __shfl(c, rd * 16 + k, 64);
            const float a = sh[(long)rk * 64 + lane];    // coalesced 256B row
            const float b = sh[(long)ck * 64 + lane];    // coalesced 256B row
            t[k * TW + lane] = a * b;                    // banks (k+lane)%32: conflict-free
        }

        // ---- phase B: transpose read + in-register segmented reduce ----
        float v[16];
        #pragma unroll
        for (int j = 0; j < 16; ++j) v[j] = t[rbase + j];  // 2 lanes/bank: free

        const float t13  = v[1] + v[2] + v[3];
        const float t48  = ((v[4] + v[5]) + (v[6] + v[7])) + v[8];
        const float t915 = ((v[9] + v[10]) + (v[11] + v[12]))
                         + ((v[13] + v[14]) + v[15]);

        // Cross-quarter fixup: q2 exports features 32..35 (v0+t13),
        // q3 exports feature 48 (v0); q1/q2 pull from lane+16.
        float exp_val = 0.0f;
        if (q == 2) exp_val = v[0] + t13;
        if (q == 3) exp_val = v[0];
        const float got = __shfl(exp_val, (lane + 16) & 63, 64);

        const long e = e_base + rd * 16 + sub;
        if (e < (long)E) {
            float* o = out + e * 8;
            if (q == 0) {
                // l=0:[0]  l=1:[1..3]  l=2:[4..8]  l=3:[9..15]
                *(float4*)o = make_float4(v[0], t13, t48, t915);
            } else if (q == 1) {
                // l=4:[16..24] = v0+t13+t48 ; l=5:[25..35] = t915 + (q2's 32..35)
                *(float2*)(o + 4) = make_float2((v[0] + t13) + t48, t915 + got);
            } else if (q == 2) {
                // l=6:[36..48] = t48+t915 + (q3's feature 48)
                o[6] = (t48 + t915) + got;
            } else {
                // l=7:[49..63] = v1..v15
                o[7] = (t13 + t48) + t915;
            }
        }
    }
}

extern "C" void kernel_launch(void* const* d_in, const int* in_sizes, int n_in,
                              void* d_out, int out_size, void* d_ws, size_t ws_size,
                              hipStream_t stream) {
    const int* edge_index = (const int*)d_in[0];   // [2, E] int32
    const float* node_sh  = (const float*)d_in[1]; // [N, 64] f32
    float* out            = (float*)d_out;         // [E, 8] f32

    const int E = in_sizes[0] / 2;
    const int* row = edge_index;
    const int* col = edge_index + E;

    const int edges_per_block = WPB * 64;
    const int blocks = (E + edges_per_block - 1) / edges_per_block;

    sh_msg_kernel<<<blocks, WPB * 64, 0, stream>>>(row, col, node_sh, out, E);
}